// Round 13
// baseline (297.009 us; speedup 1.0000x reference)
//
#include <hip/hip_runtime.h>
#include <math.h>

// Problem constants (NomicBertAttention): B=2, S=4096, DM=768, H=12, HD=64
#define B_   2
#define S_   4096
#define DM_  768
#define H_   12
#define HD_  64
#define M_   (B_ * S_)                 // 8192 rows
#define ROWELEMS ((size_t)M_ * DM_)    // 6291456 elems per [M,DM] buffer
#define WELEMS  ((size_t)DM_ * DM_)    // 589824 elems per weight

// net softmax scale: SCALING*SCALING = 1/64, times log2(e) so v_exp_f32 (2^x)
// computes e^(score/64) directly.  Folded into Q in the QKV-GEMM epilogue.
#define QSC (1.4426950408889634f / 64.0f)

typedef unsigned short u16;
typedef unsigned int   u32;
typedef __attribute__((ext_vector_type(8))) short  short8;   // 8 x bf16 (4 VGPR)
typedef __attribute__((ext_vector_type(4))) float  floatx4;  // MFMA accumulator

__device__ inline u16 f2bf(float f) {                 // RNE round
    u32 u = __builtin_bit_cast(u32, f);
    u += 0x7FFF + ((u >> 16) & 1);
    return (u16)(u >> 16);
}
__device__ inline float bf2f(u16 h) {
    return __builtin_bit_cast(float, (u32)h << 16);
}
__device__ inline u32 pk_trunc(float a, float b) {    // [bf16(b)<<16 | bf16(a)], truncate
    return __builtin_amdgcn_perm(__builtin_bit_cast(u32, b),
                                 __builtin_bit_cast(u32, a), 0x07060302);
}

// XOR-swizzled LDS offset, pitch 64 bf16 (128 B) rows:
// element (r, c) lives at r*64 + ((c/8 ^ (r&7))*8) + c%8.
__device__ inline int sw_off(int r, int cg) {         // cg = c>>3 (8-elem group)
    return (r << 6) + ((cg ^ (r & 7)) << 3);
}

// Async global->LDS 16B DMA (global_load_lds_dwordx4). LDS dest is
// wave-uniform base + lane*16; we permute the per-lane GLOBAL address so the
// content lands in the swizzled layout (same 128B lines -> still coalesced).
__device__ __forceinline__ void load_lds16(const u16* g, u16* l) {
    __builtin_amdgcn_global_load_lds(
        (const __attribute__((address_space(1))) u32*)g,
        (__attribute__((address_space(3))) u32*)l, 16, 0, 0);
}

// Explicit vmcnt(0) drain: simm16 = lgkmcnt(15)|expcnt(7)|vmcnt(0) = 0xF70.
// R11 failed post-timing validation with a timing-dependent divergence; the
// DMA->barrier visibility must not depend on the compiler's barrier lowering
// emitting the vmcnt drain. R12 confirmed this fixes it at zero cost.
__device__ __forceinline__ void drain_vm() {
    __builtin_amdgcn_s_waitcnt(0x0F70);
}

// =====================================================================
// fp32 -> bf16 conversion: y=0 hidden [M,DM]; y=1..4 weights [DM,DM]
// =====================================================================
__global__ __launch_bounds__(256) void conv_bf16(
    const float* __restrict__ h,  const float* __restrict__ wq,
    const float* __restrict__ wk, const float* __restrict__ wv,
    const float* __restrict__ wo, u16* __restrict__ hb, u16* __restrict__ wb)
{
    const int y = blockIdx.y;
    const float* src; u16* dst; size_t n4;
    if (y == 0)      { src = h;  dst = hb;              n4 = ROWELEMS / 4; }
    else if (y == 1) { src = wq; dst = wb;              n4 = WELEMS / 4; }
    else if (y == 2) { src = wk; dst = wb + WELEMS;     n4 = WELEMS / 4; }
    else if (y == 3) { src = wv; dst = wb + 2 * WELEMS; n4 = WELEMS / 4; }
    else             { src = wo; dst = wb + 3 * WELEMS; n4 = WELEMS / 4; }
    const size_t stride = (size_t)gridDim.x * 256;
    for (size_t i = blockIdx.x * 256 + threadIdx.x; i < n4; i += stride) {
        float4 v = *(const float4*)&src[i * 4];
        u32 p0 = (u32)f2bf(v.x) | ((u32)f2bf(v.y) << 16);
        u32 p1 = (u32)f2bf(v.z) | ((u32)f2bf(v.w) << 16);
        *(uint2*)&dst[i * 4] = make_uint2(p0, p1);
    }
}

// =====================================================================
// Fused QKV GEMM + RoPE + head-major repack.
// 128x128 tile, BK=64, 2x2 waves, 16x16x32 MFMA, global_load_lds staging
// into swizzled LDS.
// Epilogue z=0/1: rope -> PAIR-INTERLEAVED Qh/Kh rows (u32 slot hd1 holds
// the rotated pair (hd1, hd1+32)); dot products are invariant under a
// fixed permutation applied to BOTH Q and K rows, so flash is unchanged.
// Epilogue z=2: transpose -> Vt[B,H,HD,S].
// =====================================================================
__global__ __launch_bounds__(256, 3) void gemm_qkv(
    const u16* __restrict__ A,
    const u16* __restrict__ W0, const u16* __restrict__ W1, const u16* __restrict__ W2,
    const float* __restrict__ b0, const float* __restrict__ b1, const float* __restrict__ b2,
    const float* __restrict__ cosT, const float* __restrict__ sinT,
    u16* __restrict__ Qh, u16* __restrict__ Kh, u16* __restrict__ Vt)
{
    __shared__ __align__(16) u16 As[128 * 64];   // 16 KB, swizzled
    __shared__ __align__(16) u16 Ws[128 * 64];   // 16 KB, swizzled

    const int tid  = threadIdx.x;
    const int wave = tid >> 6, lane = tid & 63;
    const int n16  = lane & 15, quad = lane >> 4;
    const int wm   = wave >> 1, wn = wave & 1;
    const int m0   = blockIdx.y * 128, n0 = blockIdx.x * 128;
    const int z    = blockIdx.z;

    const u16* Wz = (z == 0) ? W0 : (z == 1) ? W1 : W2;
    const float* bz = (z == 0) ? b0 : (z == 1) ? b1 : b2;

    // staging lane constants: granule g covers (r, content-group cg = slot^(r&7))
    int gao[4], ldso[4];
#pragma unroll
    for (int i = 0; i < 4; i++) {
        int g = wave * 256 + i * 64 + lane;      // 0..1023
        int r = g >> 3, cg = (g & 7) ^ (r & 7);
        gao[i]  = r * DM_ + cg * 8;
        ldso[i] = (wave * 256 + i * 64) * 8;
    }
    const u16* Ap = A  + (size_t)m0 * DM_;
    const u16* Wp = Wz + (size_t)n0 * DM_;

    floatx4 acc[4][4];
#pragma unroll
    for (int i = 0; i < 4; i++)
#pragma unroll
        for (int j = 0; j < 4; j++) acc[i][j] = (floatx4){0.f, 0.f, 0.f, 0.f};

    for (int k0 = 0; k0 < DM_; k0 += 64) {
        __syncthreads();                          // prev tile fully read
#pragma unroll
        for (int i = 0; i < 4; i++) {
            load_lds16(Ap + k0 + gao[i], &As[ldso[i]]);
            load_lds16(Wp + k0 + gao[i], &Ws[ldso[i]]);
        }
        drain_vm();                               // DMA data LDS-visible
        __syncthreads();                          // tile landed for ALL waves
#pragma unroll
        for (int ks = 0; ks < 2; ks++) {
            short8 af[4], bf[4];
#pragma unroll
            for (int t = 0; t < 4; t++) {
                af[t] = *(const short8*)&As[sw_off(wm * 64 + t * 16 + n16, ks * 4 + quad)];
                bf[t] = *(const short8*)&Ws[sw_off(wn * 64 + t * 16 + n16, ks * 4 + quad)];
            }
#pragma unroll
            for (int i = 0; i < 4; i++)
#pragma unroll
                for (int j = 0; j < 4; j++)
                    acc[i][j] = __builtin_amdgcn_mfma_f32_16x16x32_bf16(
                        af[i], bf[j], acc[i][j], 0, 0, 0);
        }
    }

    // ---- epilogue: C/D layout col = n16, row = quad*4+r ----
    if (z == 2) {
#pragma unroll
        for (int i = 0; i < 4; i++)
#pragma unroll
            for (int j = 0; j < 4; j++) {
                const int col = n0 + wn * 64 + j * 16 + n16;
                const int h = col >> 6, hd = col & 63;
                const int row0 = m0 + wm * 64 + i * 16 + quad * 4;
                const int b = row0 >> 12, s0 = row0 & 4095;
                const float bias = bz[col];
                float v0 = acc[i][j][0] + bias, v1 = acc[i][j][1] + bias;
                float v2 = acc[i][j][2] + bias, v3 = acc[i][j][3] + bias;
                u32 w0 = (u32)f2bf(v0) | ((u32)f2bf(v1) << 16);
                u32 w1 = (u32)f2bf(v2) | ((u32)f2bf(v3) << 16);
                *(uint2*)&Vt[((size_t)(b * H_ + h) * HD_ + hd) * S_ + s0] = make_uint2(w0, w1);
            }
    } else {
        u32* Out32 = (u32*)((z == 0) ? Qh : Kh);
        const float sc_ = (z == 0) ? QSC : 1.0f;
#pragma unroll
        for (int i = 0; i < 4; i++)
#pragma unroll
            for (int j = 0; j < 2; j++) {
                const int col1 = n0 + wn * 64 + j * 16 + n16;   // hd1 < 32
                const int col2 = col1 + 32;
                const int h = col1 >> 6, hd1 = col1 & 63;       // hd1 in [0,32)
                const float bias1 = bz[col1], bias2 = bz[col2];
#pragma unroll
                for (int r = 0; r < 4; r++) {
                    const int row = m0 + wm * 64 + i * 16 + quad * 4 + r;
                    const int b = row >> 12, s = row & 4095;
                    const float c  = cosT[s * HD_ + hd1];
                    const float sn = sinT[s * HD_ + hd1];
                    const float x1 = acc[i][j][r] + bias1;
                    const float x2 = acc[i][j + 2][r] + bias2;
                    const float y1 = (x1 * c - x2 * sn) * sc_;
                    const float y2 = (x2 * c + x1 * sn) * sc_;
                    // pair-interleaved: u32 slot hd1 of the 32-u32 row
                    Out32[(((size_t)(b * H_ + h) * S_ + s) << 5) + hd1] =
                        (u32)f2bf(y1) | ((u32)f2bf(y2) << 16);
                }
            }
    }
}

// =====================================================================
// Flash attention, bf16 MFMA, static softmax, 2-way split-K.
// R6/R12 structure: single-buffered LDS staging via global_load_lds,
// 2 barriers/iter + explicit vmcnt drain, 128-row Q-tile (wave owns 32
// rows), S^T = K*Q^T (b64 P-pack). l (softmax denominator) accumulated
// via ones-MFMA on the matrix pipe (R12 showed VALUBusy 42% > MfmaUtil
// 36% -- the 32 scalar l-adds/iter were the tallest removable VALU
// chunk; R7 verified this l path end-to-end).
// __launch_bounds__(256,4): VGPR cap 128 (alloc ~72, NO spills).
// DO NOT raise to (256,5): R10 showed the allocator is forced to 48
// VGPR -> 628 MB scratch spill -> 4x slower.
// =====================================================================
__global__ __launch_bounds__(256, 4) void flash_mfma(
    const u16* __restrict__ Qh, const u16* __restrict__ Kh,
    const u16* __restrict__ Vt, u16* __restrict__ O1, u16* __restrict__ O2,
    float* __restrict__ l1, float* __restrict__ l2)
{
    __shared__ __align__(16) u16 Ks[64 * 64];     //  8 KB  K[kcol][d]   swizzled
    __shared__ __align__(16) u16 Vs[64 * 64];     //  8 KB  V^T[d][kcol] swizzled
    __shared__ __align__(16) u16 Ps[128 * 64];    // 16 KB  P[qrow][kcol] swizzled

    const int tid  = threadIdx.x;
    const int wave = tid >> 6, lane = tid & 63;
    const int n16  = lane & 15, quad = lane >> 4;
    const int qt   = blockIdx.x;
    const int bh   = blockIdx.y;
    const int z    = blockIdx.z;
    const size_t qk_base = (size_t)bh * S_ * HD_;
    const size_t vt_base = (size_t)bh * HD_ * S_;
    const int q0   = qt * 128;
    const int wrow = wave * 32;

    // Q fragments in registers (A/B frag layout: lane&15 x (quad*8+j))
    short8 qf[2][2];
#pragma unroll
    for (int rt = 0; rt < 2; rt++)
#pragma unroll
        for (int ks = 0; ks < 2; ks++)
            qf[rt][ks] = *(const short8*)&Qh[qk_base +
                (size_t)(q0 + wrow + rt * 16 + n16) * HD_ + ks * 32 + quad * 8];

    short8 ones;
#pragma unroll
    for (int j = 0; j < 8; j++) ones[j] = (short)0x3F80;   // bf16 1.0

    // staging lane constants (swizzled global addresses)
    int gk_off[2], gv_off[2], ldso[2];
#pragma unroll
    for (int i = 0; i < 2; i++) {
        int g = wave * 128 + i * 64 + lane;       // 0..511
        int r = g >> 3, cg = (g & 7) ^ (r & 7);
        gk_off[i] = r * HD_ + cg * 8;
        gv_off[i] = r * S_  + cg * 8;
        ldso[i]   = (wave * 128 + i * 64) * 8;
    }

    floatx4 o_acc[2][4];
    floatx4 o_l[2];                   // l accumulator (ones-MFMA, C-layout)
#pragma unroll
    for (int rt = 0; rt < 2; rt++) {
        o_l[rt] = (floatx4){0.f, 0.f, 0.f, 0.f};
#pragma unroll
        for (int dt = 0; dt < 4; dt++) o_acc[rt][dt] = (floatx4){0.f, 0.f, 0.f, 0.f};
    }

    const u16* Kg = Kh + qk_base + (size_t)(z * 32) * 64 * HD_;
    const u16* Vg = Vt + vt_base + (size_t)(z * 32) * 64;

    for (int kt = 0; kt < 32; kt++) {
        __syncthreads();                          // prev tile fully read
#pragma unroll
        for (int i = 0; i < 2; i++) {
            load_lds16(Kg + gk_off[i], &Ks[ldso[i]]);
            load_lds16(Vg + gv_off[i], &Vs[ldso[i]]);
        }
        drain_vm();                               // DMA data LDS-visible
        __syncthreads();                          // tile landed for ALL waves
        Kg += 64 * HD_;
        Vg += 64;

        // ---- S^T = K Q^T : D[m=kcol][n=qrow] ----
        floatx4 sct[4][2];
#pragma unroll
        for (int ct = 0; ct < 4; ct++)
#pragma unroll
            for (int rt = 0; rt < 2; rt++)
                sct[ct][rt] = (floatx4){0.f, 0.f, 0.f, 0.f};
#pragma unroll
        for (int ks = 0; ks < 2; ks++) {
            short8 kf[4];
#pragma unroll
            for (int ct = 0; ct < 4; ct++)
                kf[ct] = *(const short8*)&Ks[sw_off(ct * 16 + n16, ks * 4 + quad)];
#pragma unroll
            for (int ct = 0; ct < 4; ct++)
#pragma unroll
                for (int rt = 0; rt < 2; rt++)
                    sct[ct][rt] = __builtin_amdgcn_mfma_f32_16x16x32_bf16(
                        kf[ct], qf[rt][ks], sct[ct][rt], 0, 0, 0);
        }

        // ---- P = exp2(S^T): pack b64 to LDS (no VALU l-adds) ----
#pragma unroll
        for (int rt = 0; rt < 2; rt++)
#pragma unroll
            for (int ct = 0; ct < 4; ct++) {
                float p0 = __builtin_amdgcn_exp2f(sct[ct][rt][0]);
                float p1 = __builtin_amdgcn_exp2f(sct[ct][rt][1]);
                float p2 = __builtin_amdgcn_exp2f(sct[ct][rt][2]);
                float p3 = __builtin_amdgcn_exp2f(sct[ct][rt][3]);
                uint2 w = make_uint2(pk_trunc(p0, p1), pk_trunc(p2, p3));
                const int row = wrow + rt * 16 + n16;
                const int off = sw_off(row, ct * 2 + (quad >> 1)) + (quad & 1) * 4;
                *(uint2*)&Ps[off] = w;
            }
        // no barrier: Ps rows wrow..wrow+31 are wave-private (same-wave DS
        // ordering + compiler lgkmcnt covers the write->read dependency)

        // ---- O += P V ; l += P * ones (matrix pipe) ----
#pragma unroll
        for (int ks = 0; ks < 2; ks++) {
            short8 pa[2];
#pragma unroll
            for (int rt = 0; rt < 2; rt++)
                pa[rt] = *(const short8*)&Ps[sw_off(wrow + rt * 16 + n16, ks * 4 + quad)];
            short8 vb[4];
#pragma unroll
            for (int dt = 0; dt < 4; dt++)
                vb[dt] = *(const short8*)&Vs[sw_off(dt * 16 + n16, ks * 4 + quad)];
#pragma unroll
            for (int rt = 0; rt < 2; rt++) {
#pragma unroll
                for (int dt = 0; dt < 4; dt++)
                    o_acc[rt][dt] = __builtin_amdgcn_mfma_f32_16x16x32_bf16(
                        pa[rt], vb[dt], o_acc[rt][dt], 0, 0, 0);
                o_l[rt] = __builtin_amdgcn_mfma_f32_16x16x32_bf16(
                    pa[rt], ones, o_l[rt], 0, 0, 0);
            }
        }
    }

    // ---- epilogue: l from C-layout (row=quad*4+r, all cols equal; R7
    // verified) + raw partial O writes ----
    float* lz = z ? l2 : l1;
    if (n16 == 0) {
#pragma unroll
        for (int rt = 0; rt < 2; rt++)
#pragma unroll
            for (int r = 0; r < 4; r++)
                lz[(size_t)bh * S_ + q0 + wrow + rt * 16 + quad * 4 + r] = o_l[rt][r];
    }
    const int b = bh / H_, h = bh % H_;
    u16* Oz = z ? O2 : O1;
#pragma unroll
    for (int rt = 0; rt < 2; rt++)
#pragma unroll
        for (int r = 0; r < 4; r++) {
            const int srow = q0 + wrow + rt * 16 + quad * 4 + r;
            u16* Orow = Oz + ((size_t)b * S_ + srow) * DM_ + h * HD_;
#pragma unroll
            for (int dt = 0; dt < 4; dt++)
                Orow[dt * 16 + n16] = f2bf(o_acc[rt][dt][r]);
        }
}

// =====================================================================
// Out-proj GEMM with fused split-K merge:
//   A = (O1+O2) / (l1+l2)  computed during A-staging (VGPR path),
//   W staged via global_load_lds.  out = A @ Wo^T + hidden (fp32).
// Tile 64(m) x 128(n), BK=64, 2x2 waves (wave: 32 rows x 64 cols).
// =====================================================================
__global__ __launch_bounds__(256, 4) void gemm_out(
    const u16* __restrict__ O1, const u16* __restrict__ O2,
    const float* __restrict__ l1, const float* __restrict__ l2,
    const u16* __restrict__ W, const float* __restrict__ resid,
    float* __restrict__ Cf)
{
    __shared__ __align__(16) u16 As[64 * 64];     //  8 KB, swizzled
    __shared__ __align__(16) u16 Ws[128 * 64];    // 16 KB, swizzled

    const int tid  = threadIdx.x;
    const int wave = tid >> 6, lane = tid & 63;
    const int n16  = lane & 15, quad = lane >> 4;
    const int wm   = wave >> 1, wn = wave & 1;
    const int m0   = blockIdx.y * 64, n0 = blockIdx.x * 128;

    int gwo[4], ldswo[4];
#pragma unroll
    for (int i = 0; i < 4; i++) {
        int g = wave * 256 + i * 64 + lane;
        int r = g >> 3, cg = (g & 7) ^ (r & 7);
        gwo[i]   = r * DM_ + cg * 8;
        ldswo[i] = (wave * 256 + i * 64) * 8;
    }
    const u16* Wp = W + (size_t)n0 * DM_;

    floatx4 acc[2][4];
#pragma unroll
    for (int i = 0; i < 2; i++)
#pragma unroll
        for (int j = 0; j < 4; j++) acc[i][j] = (floatx4){0.f, 0.f, 0.f, 0.f};

    for (int k0 = 0; k0 < DM_; k0 += 64) {
        __syncthreads();
#pragma unroll
        for (int i = 0; i < 4; i++)
            load_lds16(Wp + k0 + gwo[i], &Ws[ldswo[i]]);

        // A staging with fused merge: 512 granules, 2 per thread
#pragma unroll
        for (int i = 0; i < 2; i++) {
            const int ga = tid + i * 256;
            const int ra = ga >> 3, cga = ga & 7;
            const int row = m0 + ra;
            const int col0 = k0 + cga * 8;
            const int b = row >> 12, s = row & 4095, h = col0 >> 6;
            const size_t lidx = ((size_t)(b * H_ + h)) * S_ + s;
            const float inv = __builtin_amdgcn_rcpf(l1[lidx] + l2[lidx]);
            const size_t go = (size_t)row * DM_ + col0;
            uint4 a = *(const uint4*)&O1[go];
            uint4 c = *(const uint4*)&O2[go];
            u32 res[4];
#pragma unroll
            for (int w = 0; w < 4; w++) {
                u32 ua = (&a.x)[w], uc = (&c.x)[w];
                float x0 = bf2f((u16)(ua & 0xFFFF)) + bf2f((u16)(uc & 0xFFFF));
                float x1 = bf2f((u16)(ua >> 16))    + bf2f((u16)(uc >> 16));
                res[w] = (u32)f2bf(x0 * inv) | ((u32)f2bf(x1 * inv) << 16);
            }
            *(uint4*)&As[sw_off(ra, cga)] = make_uint4(res[0], res[1], res[2], res[3]);
        }
        drain_vm();                               // W-DMA data LDS-visible
        __syncthreads();

#pragma unroll
        for (int ks = 0; ks < 2; ks++) {
            short8 af[2], bf[4];
#pragma unroll
            for (int rt = 0; rt < 2; rt++)
                af[rt] = *(const short8*)&As[sw_off(wm * 32 + rt * 16 + n16, ks * 4 + quad)];
#pragma unroll
            for (int ct = 0; ct < 4; ct++)
                bf[ct] = *(const short8*)&Ws[sw_off(wn * 64 + ct * 16 + n16, ks * 4 + quad)];
#pragma unroll
            for (int rt = 0; rt < 2; rt++)
#pragma unroll
                for (int ct = 0; ct < 4; ct++)
                    acc[rt][ct] = __builtin_amdgcn_mfma_f32_16x16x32_bf16(
                        af[rt], bf[ct], acc[rt][ct], 0, 0, 0);
        }
    }

#pragma unroll
    for (int rt = 0; rt < 2; rt++)
#pragma unroll
        for (int ct = 0; ct < 4; ct++) {
            const int col = n0 + wn * 64 + ct * 16 + n16;
#pragma unroll
            for (int r = 0; r < 4; r++) {
                const int row = m0 + wm * 32 + rt * 16 + quad * 4 + r;
                Cf[(size_t)row * DM_ + col] = acc[rt][ct][r] + resid[(size_t)row * DM_ + col];
            }
        }
}

// =====================================================================
// LayerNorm in-place on [M, DM] rows. grid: M, block: 192 (float4/thread)
// =====================================================================
__global__ __launch_bounds__(192) void ln_kernel(
    float* __restrict__ io, const float* __restrict__ g, const float* __restrict__ bb)
{
    const int row = blockIdx.x, t = threadIdx.x;
    float* p = io + (size_t)row * DM_;
    float4 x = *(const float4*)&p[t * 4];
    float sum = (x.x + x.y) + (x.z + x.w);
    float sq  = fmaf(x.x, x.x, fmaf(x.y, x.y, fmaf(x.z, x.z, x.w * x.w)));
#pragma unroll
    for (int off = 32; off >= 1; off >>= 1) {
        sum += __shfl_xor(sum, off);
        sq  += __shfl_xor(sq, off);
    }
    __shared__ float s1[3], s2[3];
    if ((t & 63) == 0) { s1[t >> 6] = sum; s2[t >> 6] = sq; }
    __syncthreads();
    sum = s1[0] + s1[1] + s1[2];
    sq  = s2[0] + s2[1] + s2[2];
    const float mu  = sum * (1.0f / 768.0f);
    const float var = sq * (1.0f / 768.0f) - mu * mu;
    const float rs  = rsqrtf(var + 1e-12f);
    float4 g4 = *(const float4*)&g[t * 4];
    float4 b4 = *(const float4*)&bb[t * 4];
    float4 o;
    o.x = (x.x - mu) * rs * g4.x + b4.x;
    o.y = (x.y - mu) * rs * g4.y + b4.y;
    o.z = (x.z - mu) * rs * g4.z + b4.z;
    o.w = (x.w - mu) * rs * g4.w + b4.w;
    *(float4*)&p[t * 4] = o;
}

// =====================================================================
// Workspace (bf16 elem offsets; total ~68.4 MB <= proven 75.5 MB):
//   Hb [0,R)      -> O1 overlays after gemm_qkv
//   Wb [R, R+4W)
//   Qh, Kh, Vt    (R each)
//   O2 [4R+4W, 5R+4W)
//   l1,l2 fp32    [5R+4W ...)  (2 * B*H*S floats)
// =====================================================================
extern "C" void kernel_launch(void* const* d_in, const int* in_sizes, int n_in,
                              void* d_out, int out_size, void* d_ws, size_t ws_size,
                              hipStream_t stream)
{
    const float* hidden = (const float*)d_in[0];
    const float* cosT   = (const float*)d_in[1];
    const float* sinT   = (const float*)d_in[2];
    const float* Wq     = (const float*)d_in[3];
    const float* bq     = (const float*)d_in[4];
    const float* Wk     = (const float*)d_in[5];
    const float* bk     = (const float*)d_in[6];
    const float* Wv     = (const float*)d_in[7];
    const float* bv     = (const float*)d_in[8];
    const float* Wo     = (const float*)d_in[9];
    const float* ln_g   = (const float*)d_in[10];
    const float* ln_b   = (const float*)d_in[11];
    float* out = (float*)d_out;

    u16* wsb = (u16*)d_ws;
    u16* Hb  = wsb;
    u16* Wb  = wsb + ROWELEMS;
    u16* Qh  = Wb + 4 * WELEMS;
    u16* Kh  = Qh + ROWELEMS;
    u16* Vt  = Kh + ROWELEMS;
    u16* O2  = Vt + ROWELEMS;
    float* l1 = (float*)(O2 + ROWELEMS);
    float* l2 = l1 + (size_t)B_ * H_ * S_;
    u16* O1  = Hb;                        // overlays Hb (dead after gemm_qkv)
    u16* Wqb = Wb, *Wkb = Wb + WELEMS, *Wvb = Wb + 2 * WELEMS, *Wob = Wb + 3 * WELEMS;

    conv_bf16<<<dim3(1024, 5), 256, 0, stream>>>(hidden, Wq, Wk, Wv, Wo, Hb, Wb);

    gemm_qkv<<<dim3(DM_ / 128, M_ / 128, 3), 256, 0, stream>>>(
        Hb, Wqb, Wkb, Wvb, bq, bk, bv, cosT, sinT, Qh, Kh, Vt);

    flash_mfma<<<dim3(S_ / 128, B_ * H_, 2), 256, 0, stream>>>(
        Qh, Kh, Vt, O1, O2, l1, l2);

    gemm_out<<<dim3(DM_ / 128, M_ / 64), 256, 0, stream>>>(
        O1, O2, l1, l2, Wob, hidden, out);

    ln_kernel<<<M_, 192, 0, stream>>>(out, ln_g, ln_b);
}

// Round 14
// 278.494 us; speedup vs baseline: 1.0665x; 1.0665x over previous
//
#include <hip/hip_runtime.h>
#include <math.h>

// Problem constants (NomicBertAttention): B=2, S=4096, DM=768, H=12, HD=64
#define B_   2
#define S_   4096
#define DM_  768
#define H_   12
#define HD_  64
#define M_   (B_ * S_)                 // 8192 rows
#define ROWELEMS ((size_t)M_ * DM_)    // 6291456 elems per [M,DM] buffer
#define WELEMS  ((size_t)DM_ * DM_)    // 589824 elems per weight

// net softmax scale: SCALING*SCALING = 1/64, times log2(e) so v_exp_f32 (2^x)
// computes e^(score/64) directly.  Folded into Q in the QKV-GEMM epilogue.
#define QSC (1.4426950408889634f / 64.0f)

typedef unsigned short u16;
typedef unsigned int   u32;
typedef __attribute__((ext_vector_type(8))) short  short8;   // 8 x bf16 (4 VGPR)
typedef __attribute__((ext_vector_type(4))) float  floatx4;  // MFMA accumulator

__device__ inline u16 f2bf(float f) {                 // RNE round
    u32 u = __builtin_bit_cast(u32, f);
    u += 0x7FFF + ((u >> 16) & 1);
    return (u16)(u >> 16);
}
__device__ inline float bf2f(u16 h) {
    return __builtin_bit_cast(float, (u32)h << 16);
}
__device__ inline u32 pk_trunc(float a, float b) {    // [bf16(b)<<16 | bf16(a)], truncate
    return __builtin_amdgcn_perm(__builtin_bit_cast(u32, b),
                                 __builtin_bit_cast(u32, a), 0x07060302);
}

// XOR-swizzled LDS offset, pitch 64 bf16 (128 B) rows:
// element (r, c) lives at r*64 + ((c/8 ^ (r&7))*8) + c%8.
__device__ inline int sw_off(int r, int cg) {         // cg = c>>3 (8-elem group)
    return (r << 6) + ((cg ^ (r & 7)) << 3);
}

// Async global->LDS 16B DMA (global_load_lds_dwordx4). LDS dest is
// wave-uniform base + lane*16; we permute the per-lane GLOBAL address so the
// content lands in the swizzled layout (same 128B lines -> still coalesced).
__device__ __forceinline__ void load_lds16(const u16* g, u16* l) {
    __builtin_amdgcn_global_load_lds(
        (const __attribute__((address_space(1))) u32*)g,
        (__attribute__((address_space(3))) u32*)l, 16, 0, 0);
}

// Explicit vmcnt(0) drain: simm16 = lgkmcnt(15)|expcnt(7)|vmcnt(0) = 0xF70.
// R11 failed post-timing validation with a timing-dependent divergence; the
// DMA->barrier visibility must not depend on the compiler's barrier lowering
// emitting the vmcnt drain. R12 confirmed this fixes it at zero cost.
__device__ __forceinline__ void drain_vm() {
    __builtin_amdgcn_s_waitcnt(0x0F70);
}

// =====================================================================
// fp32 -> bf16 conversion: y=0 hidden [M,DM]; y=1..4 weights [DM,DM]
// =====================================================================
__global__ __launch_bounds__(256) void conv_bf16(
    const float* __restrict__ h,  const float* __restrict__ wq,
    const float* __restrict__ wk, const float* __restrict__ wv,
    const float* __restrict__ wo, u16* __restrict__ hb, u16* __restrict__ wb)
{
    const int y = blockIdx.y;
    const float* src; u16* dst; size_t n4;
    if (y == 0)      { src = h;  dst = hb;              n4 = ROWELEMS / 4; }
    else if (y == 1) { src = wq; dst = wb;              n4 = WELEMS / 4; }
    else if (y == 2) { src = wk; dst = wb + WELEMS;     n4 = WELEMS / 4; }
    else if (y == 3) { src = wv; dst = wb + 2 * WELEMS; n4 = WELEMS / 4; }
    else             { src = wo; dst = wb + 3 * WELEMS; n4 = WELEMS / 4; }
    const size_t stride = (size_t)gridDim.x * 256;
    for (size_t i = blockIdx.x * 256 + threadIdx.x; i < n4; i += stride) {
        float4 v = *(const float4*)&src[i * 4];
        u32 p0 = (u32)f2bf(v.x) | ((u32)f2bf(v.y) << 16);
        u32 p1 = (u32)f2bf(v.z) | ((u32)f2bf(v.w) << 16);
        *(uint2*)&dst[i * 4] = make_uint2(p0, p1);
    }
}

// =====================================================================
// Fused QKV GEMM + RoPE + head-major repack.
// 128x128 tile, BK=64, 2x2 waves, 16x16x32 MFMA, global_load_lds staging
// into swizzled LDS.
// Epilogue z=0/1: rope -> PAIR-INTERLEAVED Qh/Kh rows (u32 slot hd1 holds
// the rotated pair (hd1, hd1+32)); dot products are invariant under a
// fixed permutation applied to BOTH Q and K rows, so flash is unchanged.
// Epilogue z=2: transpose -> Vt[B,H,HD,S].
// =====================================================================
__global__ __launch_bounds__(256, 3) void gemm_qkv(
    const u16* __restrict__ A,
    const u16* __restrict__ W0, const u16* __restrict__ W1, const u16* __restrict__ W2,
    const float* __restrict__ b0, const float* __restrict__ b1, const float* __restrict__ b2,
    const float* __restrict__ cosT, const float* __restrict__ sinT,
    u16* __restrict__ Qh, u16* __restrict__ Kh, u16* __restrict__ Vt)
{
    __shared__ __align__(16) u16 As[128 * 64];   // 16 KB, swizzled
    __shared__ __align__(16) u16 Ws[128 * 64];   // 16 KB, swizzled

    const int tid  = threadIdx.x;
    const int wave = tid >> 6, lane = tid & 63;
    const int n16  = lane & 15, quad = lane >> 4;
    const int wm   = wave >> 1, wn = wave & 1;
    const int m0   = blockIdx.y * 128, n0 = blockIdx.x * 128;
    const int z    = blockIdx.z;

    const u16* Wz = (z == 0) ? W0 : (z == 1) ? W1 : W2;
    const float* bz = (z == 0) ? b0 : (z == 1) ? b1 : b2;

    // staging lane constants: granule g covers (r, content-group cg = slot^(r&7))
    int gao[4], ldso[4];
#pragma unroll
    for (int i = 0; i < 4; i++) {
        int g = wave * 256 + i * 64 + lane;      // 0..1023
        int r = g >> 3, cg = (g & 7) ^ (r & 7);
        gao[i]  = r * DM_ + cg * 8;
        ldso[i] = (wave * 256 + i * 64) * 8;
    }
    const u16* Ap = A  + (size_t)m0 * DM_;
    const u16* Wp = Wz + (size_t)n0 * DM_;

    floatx4 acc[4][4];
#pragma unroll
    for (int i = 0; i < 4; i++)
#pragma unroll
        for (int j = 0; j < 4; j++) acc[i][j] = (floatx4){0.f, 0.f, 0.f, 0.f};

    for (int k0 = 0; k0 < DM_; k0 += 64) {
        __syncthreads();                          // prev tile fully read
#pragma unroll
        for (int i = 0; i < 4; i++) {
            load_lds16(Ap + k0 + gao[i], &As[ldso[i]]);
            load_lds16(Wp + k0 + gao[i], &Ws[ldso[i]]);
        }
        drain_vm();                               // DMA data LDS-visible
        __syncthreads();                          // tile landed for ALL waves
#pragma unroll
        for (int ks = 0; ks < 2; ks++) {
            short8 af[4], bf[4];
#pragma unroll
            for (int t = 0; t < 4; t++) {
                af[t] = *(const short8*)&As[sw_off(wm * 64 + t * 16 + n16, ks * 4 + quad)];
                bf[t] = *(const short8*)&Ws[sw_off(wn * 64 + t * 16 + n16, ks * 4 + quad)];
            }
#pragma unroll
            for (int i = 0; i < 4; i++)
#pragma unroll
                for (int j = 0; j < 4; j++)
                    acc[i][j] = __builtin_amdgcn_mfma_f32_16x16x32_bf16(
                        af[i], bf[j], acc[i][j], 0, 0, 0);
        }
    }

    // ---- epilogue: C/D layout col = n16, row = quad*4+r ----
    if (z == 2) {
#pragma unroll
        for (int i = 0; i < 4; i++)
#pragma unroll
            for (int j = 0; j < 4; j++) {
                const int col = n0 + wn * 64 + j * 16 + n16;
                const int h = col >> 6, hd = col & 63;
                const int row0 = m0 + wm * 64 + i * 16 + quad * 4;
                const int b = row0 >> 12, s0 = row0 & 4095;
                const float bias = bz[col];
                float v0 = acc[i][j][0] + bias, v1 = acc[i][j][1] + bias;
                float v2 = acc[i][j][2] + bias, v3 = acc[i][j][3] + bias;
                u32 w0 = (u32)f2bf(v0) | ((u32)f2bf(v1) << 16);
                u32 w1 = (u32)f2bf(v2) | ((u32)f2bf(v3) << 16);
                *(uint2*)&Vt[((size_t)(b * H_ + h) * HD_ + hd) * S_ + s0] = make_uint2(w0, w1);
            }
    } else {
        u32* Out32 = (u32*)((z == 0) ? Qh : Kh);
        const float sc_ = (z == 0) ? QSC : 1.0f;
#pragma unroll
        for (int i = 0; i < 4; i++)
#pragma unroll
            for (int j = 0; j < 2; j++) {
                const int col1 = n0 + wn * 64 + j * 16 + n16;   // hd1 < 32
                const int col2 = col1 + 32;
                const int h = col1 >> 6, hd1 = col1 & 63;       // hd1 in [0,32)
                const float bias1 = bz[col1], bias2 = bz[col2];
#pragma unroll
                for (int r = 0; r < 4; r++) {
                    const int row = m0 + wm * 64 + i * 16 + quad * 4 + r;
                    const int b = row >> 12, s = row & 4095;
                    const float c  = cosT[s * HD_ + hd1];
                    const float sn = sinT[s * HD_ + hd1];
                    const float x1 = acc[i][j][r] + bias1;
                    const float x2 = acc[i][j + 2][r] + bias2;
                    const float y1 = (x1 * c - x2 * sn) * sc_;
                    const float y2 = (x2 * c + x1 * sn) * sc_;
                    // pair-interleaved: u32 slot hd1 of the 32-u32 row
                    Out32[(((size_t)(b * H_ + h) * S_ + s) << 5) + hd1] =
                        (u32)f2bf(y1) | ((u32)f2bf(y2) << 16);
                }
            }
    }
}

// =====================================================================
// Flash attention, bf16 MFMA, static softmax, NO split-K (R14):
// with (256,4) occupancy the z=2 split bought no extra concurrency
// (~3 blocks/CU resident either way) but cost double Q reads, double
// O-partial traffic, l buffers, and a VALU merge path in gemm_out.
// grid (S/128, B*H) = 768 blocks = exactly 3/CU; 64 K-iters/block.
// Epilogue normalizes O in-place (block owns the complete l via the
// ones-MFMA accumulator) -> gemm_out is a pure DMA-staged GEMM.
// R6/R12 loop structure: single-buffered LDS staging via
// global_load_lds, 2 barriers/iter + explicit vmcnt drain, 128-row
// Q-tile (wave owns 32 rows), S^T = K*Q^T (b64 P-pack).
// __launch_bounds__(256,4): VGPR cap 128 (alloc ~72, NO spills).
// DO NOT raise to (256,5): R10 showed the allocator is forced to 48
// VGPR -> 628 MB scratch spill -> 4x slower.
// =====================================================================
__global__ __launch_bounds__(256, 4) void flash_mfma(
    const u16* __restrict__ Qh, const u16* __restrict__ Kh,
    const u16* __restrict__ Vt, u16* __restrict__ O)
{
    __shared__ __align__(16) u16 Ks[64 * 64];     //  8 KB  K[kcol][d]   swizzled
    __shared__ __align__(16) u16 Vs[64 * 64];     //  8 KB  V^T[d][kcol] swizzled
    __shared__ __align__(16) u16 Ps[128 * 64];    // 16 KB  P[qrow][kcol] swizzled

    const int tid  = threadIdx.x;
    const int wave = tid >> 6, lane = tid & 63;
    const int n16  = lane & 15, quad = lane >> 4;
    const int qt   = blockIdx.x;
    const int bh   = blockIdx.y;
    const size_t qk_base = (size_t)bh * S_ * HD_;
    const size_t vt_base = (size_t)bh * HD_ * S_;
    const int q0   = qt * 128;
    const int wrow = wave * 32;

    // Q fragments in registers (A/B frag layout: lane&15 x (quad*8+j))
    short8 qf[2][2];
#pragma unroll
    for (int rt = 0; rt < 2; rt++)
#pragma unroll
        for (int ks = 0; ks < 2; ks++)
            qf[rt][ks] = *(const short8*)&Qh[qk_base +
                (size_t)(q0 + wrow + rt * 16 + n16) * HD_ + ks * 32 + quad * 8];

    short8 ones;
#pragma unroll
    for (int j = 0; j < 8; j++) ones[j] = (short)0x3F80;   // bf16 1.0

    // staging lane constants (swizzled global addresses)
    int gk_off[2], gv_off[2], ldso[2];
#pragma unroll
    for (int i = 0; i < 2; i++) {
        int g = wave * 128 + i * 64 + lane;       // 0..511
        int r = g >> 3, cg = (g & 7) ^ (r & 7);
        gk_off[i] = r * HD_ + cg * 8;
        gv_off[i] = r * S_  + cg * 8;
        ldso[i]   = (wave * 128 + i * 64) * 8;
    }

    floatx4 o_acc[2][4];
    floatx4 o_l[2];                   // l accumulator (ones-MFMA, C-layout)
#pragma unroll
    for (int rt = 0; rt < 2; rt++) {
        o_l[rt] = (floatx4){0.f, 0.f, 0.f, 0.f};
#pragma unroll
        for (int dt = 0; dt < 4; dt++) o_acc[rt][dt] = (floatx4){0.f, 0.f, 0.f, 0.f};
    }

    const u16* Kg = Kh + qk_base;
    const u16* Vg = Vt + vt_base;

    for (int kt = 0; kt < 64; kt++) {
        __syncthreads();                          // prev tile fully read
#pragma unroll
        for (int i = 0; i < 2; i++) {
            load_lds16(Kg + gk_off[i], &Ks[ldso[i]]);
            load_lds16(Vg + gv_off[i], &Vs[ldso[i]]);
        }
        drain_vm();                               // DMA data LDS-visible
        __syncthreads();                          // tile landed for ALL waves
        Kg += 64 * HD_;
        Vg += 64;

        // ---- S^T = K Q^T : D[m=kcol][n=qrow] ----
        floatx4 sct[4][2];
#pragma unroll
        for (int ct = 0; ct < 4; ct++)
#pragma unroll
            for (int rt = 0; rt < 2; rt++)
                sct[ct][rt] = (floatx4){0.f, 0.f, 0.f, 0.f};
#pragma unroll
        for (int ks = 0; ks < 2; ks++) {
            short8 kf[4];
#pragma unroll
            for (int ct = 0; ct < 4; ct++)
                kf[ct] = *(const short8*)&Ks[sw_off(ct * 16 + n16, ks * 4 + quad)];
#pragma unroll
            for (int ct = 0; ct < 4; ct++)
#pragma unroll
                for (int rt = 0; rt < 2; rt++)
                    sct[ct][rt] = __builtin_amdgcn_mfma_f32_16x16x32_bf16(
                        kf[ct], qf[rt][ks], sct[ct][rt], 0, 0, 0);
        }

        // ---- P = exp2(S^T): pack b64 to LDS ----
#pragma unroll
        for (int rt = 0; rt < 2; rt++)
#pragma unroll
            for (int ct = 0; ct < 4; ct++) {
                float p0 = __builtin_amdgcn_exp2f(sct[ct][rt][0]);
                float p1 = __builtin_amdgcn_exp2f(sct[ct][rt][1]);
                float p2 = __builtin_amdgcn_exp2f(sct[ct][rt][2]);
                float p3 = __builtin_amdgcn_exp2f(sct[ct][rt][3]);
                uint2 w = make_uint2(pk_trunc(p0, p1), pk_trunc(p2, p3));
                const int row = wrow + rt * 16 + n16;
                const int off = sw_off(row, ct * 2 + (quad >> 1)) + (quad & 1) * 4;
                *(uint2*)&Ps[off] = w;
            }
        // no barrier: Ps rows wrow..wrow+31 are wave-private (same-wave DS
        // ordering + compiler lgkmcnt covers the write->read dependency)

        // ---- O += P V ; l += P * ones (matrix pipe) ----
#pragma unroll
        for (int ks = 0; ks < 2; ks++) {
            short8 pa[2];
#pragma unroll
            for (int rt = 0; rt < 2; rt++)
                pa[rt] = *(const short8*)&Ps[sw_off(wrow + rt * 16 + n16, ks * 4 + quad)];
            short8 vb[4];
#pragma unroll
            for (int dt = 0; dt < 4; dt++)
                vb[dt] = *(const short8*)&Vs[sw_off(dt * 16 + n16, ks * 4 + quad)];
#pragma unroll
            for (int rt = 0; rt < 2; rt++) {
#pragma unroll
                for (int dt = 0; dt < 4; dt++)
                    o_acc[rt][dt] = __builtin_amdgcn_mfma_f32_16x16x32_bf16(
                        pa[rt], vb[dt], o_acc[rt][dt], 0, 0, 0);
                o_l[rt] = __builtin_amdgcn_mfma_f32_16x16x32_bf16(
                    pa[rt], ones, o_l[rt], 0, 0, 0);
            }
        }
    }

    // ---- epilogue: normalize by complete l (C-layout: row=quad*4+r, all
    // cols equal, so every lane holds its row's l) and write final bf16 O ----
    const int b = bh / H_, h = bh % H_;
#pragma unroll
    for (int rt = 0; rt < 2; rt++)
#pragma unroll
        for (int r = 0; r < 4; r++) {
            const float inv = 1.0f / o_l[rt][r];
            const int srow = q0 + wrow + rt * 16 + quad * 4 + r;
            u16* Orow = O + ((size_t)b * S_ + srow) * DM_ + h * HD_;
#pragma unroll
            for (int dt = 0; dt < 4; dt++)
                Orow[dt * 16 + n16] = f2bf(o_acc[rt][dt][r] * inv);
        }
}

// =====================================================================
// Out-proj GEMM, pure DMA-staged (R14: flash output is pre-normalized):
//   out = A @ Wo^T + hidden (fp32).  A and W both via global_load_lds.
// Tile 64(m) x 128(n), BK=64, 2x2 waves (wave: 32 rows x 64 cols).
// =====================================================================
__global__ __launch_bounds__(256, 4) void gemm_out(
    const u16* __restrict__ A, const u16* __restrict__ W,
    const float* __restrict__ resid, float* __restrict__ Cf)
{
    __shared__ __align__(16) u16 As[64 * 64];     //  8 KB, swizzled
    __shared__ __align__(16) u16 Ws[128 * 64];    // 16 KB, swizzled

    const int tid  = threadIdx.x;
    const int wave = tid >> 6, lane = tid & 63;
    const int n16  = lane & 15, quad = lane >> 4;
    const int wm   = wave >> 1, wn = wave & 1;
    const int m0   = blockIdx.y * 64, n0 = blockIdx.x * 128;

    // W: 1024 granules (4 DMA/thread); A: 512 granules (2 DMA/thread)
    int gwo[4], ldswo[4], gao[2], ldsao[2];
#pragma unroll
    for (int i = 0; i < 4; i++) {
        int g = wave * 256 + i * 64 + lane;
        int r = g >> 3, cg = (g & 7) ^ (r & 7);
        gwo[i]   = r * DM_ + cg * 8;
        ldswo[i] = (wave * 256 + i * 64) * 8;
    }
#pragma unroll
    for (int i = 0; i < 2; i++) {
        int g = wave * 128 + i * 64 + lane;       // 0..511
        int r = g >> 3, cg = (g & 7) ^ (r & 7);
        gao[i]   = r * DM_ + cg * 8;
        ldsao[i] = (wave * 128 + i * 64) * 8;
    }
    const u16* Wp = W + (size_t)n0 * DM_;
    const u16* Ap = A + (size_t)m0 * DM_;

    floatx4 acc[2][4];
#pragma unroll
    for (int i = 0; i < 2; i++)
#pragma unroll
        for (int j = 0; j < 4; j++) acc[i][j] = (floatx4){0.f, 0.f, 0.f, 0.f};

    for (int k0 = 0; k0 < DM_; k0 += 64) {
        __syncthreads();
#pragma unroll
        for (int i = 0; i < 4; i++)
            load_lds16(Wp + k0 + gwo[i], &Ws[ldswo[i]]);
#pragma unroll
        for (int i = 0; i < 2; i++)
            load_lds16(Ap + k0 + gao[i], &As[ldsao[i]]);
        drain_vm();                               // DMA data LDS-visible
        __syncthreads();

#pragma unroll
        for (int ks = 0; ks < 2; ks++) {
            short8 af[2], bf[4];
#pragma unroll
            for (int rt = 0; rt < 2; rt++)
                af[rt] = *(const short8*)&As[sw_off(wm * 32 + rt * 16 + n16, ks * 4 + quad)];
#pragma unroll
            for (int ct = 0; ct < 4; ct++)
                bf[ct] = *(const short8*)&Ws[sw_off(wn * 64 + ct * 16 + n16, ks * 4 + quad)];
#pragma unroll
            for (int rt = 0; rt < 2; rt++)
#pragma unroll
                for (int ct = 0; ct < 4; ct++)
                    acc[rt][ct] = __builtin_amdgcn_mfma_f32_16x16x32_bf16(
                        af[rt], bf[ct], acc[rt][ct], 0, 0, 0);
        }
    }

#pragma unroll
    for (int rt = 0; rt < 2; rt++)
#pragma unroll
        for (int ct = 0; ct < 4; ct++) {
            const int col = n0 + wn * 64 + ct * 16 + n16;
#pragma unroll
            for (int r = 0; r < 4; r++) {
                const int row = m0 + wm * 32 + rt * 16 + quad * 4 + r;
                Cf[(size_t)row * DM_ + col] = acc[rt][ct][r] + resid[(size_t)row * DM_ + col];
            }
        }
}

// =====================================================================
// LayerNorm in-place on [M, DM] rows. grid: M, block: 256 (R12-proven)
// =====================================================================
__global__ __launch_bounds__(256) void ln_kernel(
    float* __restrict__ io, const float* __restrict__ g, const float* __restrict__ bb)
{
    const int row = blockIdx.x, t = threadIdx.x;
    float* p = io + (size_t)row * DM_;
    float x[3];
    float sum = 0.0f, sq = 0.0f;
#pragma unroll
    for (int i = 0; i < 3; i++) {
        x[i] = p[t + i * 256];
        sum += x[i];
        sq  = fmaf(x[i], x[i], sq);
    }
#pragma unroll
    for (int off = 32; off >= 1; off >>= 1) {
        sum += __shfl_xor(sum, off);
        sq  += __shfl_xor(sq, off);
    }
    __shared__ float s1[4], s2[4];
    if ((t & 63) == 0) { s1[t >> 6] = sum; s2[t >> 6] = sq; }
    __syncthreads();
    sum = s1[0] + s1[1] + s1[2] + s1[3];
    sq  = s2[0] + s2[1] + s2[2] + s2[3];
    const float mu  = sum * (1.0f / 768.0f);
    const float var = sq * (1.0f / 768.0f) - mu * mu;
    const float rs  = rsqrtf(var + 1e-12f);
#pragma unroll
    for (int i = 0; i < 3; i++) {
        const int c = t + i * 256;
        p[c] = (x[i] - mu) * rs * g[c] + bb[c];
    }
}

// =====================================================================
// Workspace (bf16 elem offsets; total ~55.5 MB <= proven 75.5 MB):
//   Hb [0,R)      -> O (final attn out, bf16) overlays after gemm_qkv
//   Wb [R, R+4W)
//   Qh, Kh, Vt    (R each)
// =====================================================================
extern "C" void kernel_launch(void* const* d_in, const int* in_sizes, int n_in,
                              void* d_out, int out_size, void* d_ws, size_t ws_size,
                              hipStream_t stream)
{
    const float* hidden = (const float*)d_in[0];
    const float* cosT   = (const float*)d_in[1];
    const float* sinT   = (const float*)d_in[2];
    const float* Wq     = (const float*)d_in[3];
    const float* bq     = (const float*)d_in[4];
    const float* Wk     = (const float*)d_in[5];
    const float* bk     = (const float*)d_in[6];
    const float* Wv     = (const float*)d_in[7];
    const float* bv     = (const float*)d_in[8];
    const float* Wo     = (const float*)d_in[9];
    const float* ln_g   = (const float*)d_in[10];
    const float* ln_b   = (const float*)d_in[11];
    float* out = (float*)d_out;

    u16* wsb = (u16*)d_ws;
    u16* Hb  = wsb;
    u16* Wb  = wsb + ROWELEMS;
    u16* Qh  = Wb + 4 * WELEMS;
    u16* Kh  = Qh + ROWELEMS;
    u16* Vt  = Kh + ROWELEMS;
    u16* Ob  = Hb;                        // overlays Hb (dead after gemm_qkv)
    u16* Wqb = Wb, *Wkb = Wb + WELEMS, *Wvb = Wb + 2 * WELEMS, *Wob = Wb + 3 * WELEMS;

    conv_bf16<<<dim3(1024, 5), 256, 0, stream>>>(hidden, Wq, Wk, Wv, Wo, Hb, Wb);

    gemm_qkv<<<dim3(DM_ / 128, M_ / 128, 3), 256, 0, stream>>>(
        Hb, Wqb, Wkb, Wvb, bq, bk, bv, cosT, sinT, Qh, Kh, Vt);

    flash_mfma<<<dim3(S_ / 128, B_ * H_), 256, 0, stream>>>(Qh, Kh, Vt, Ob);

    gemm_out<<<dim3(DM_ / 128, M_ / 64), 256, 0, stream>>>(Ob, Wob, hidden, out);

    ln_kernel<<<M_, 256, 0, stream>>>(out, ln_g, ln_b);
}